// Round 1
// baseline (357.816 us; speedup 1.0000x reference)
//

#include <hip/hip_runtime.h>

// R20 = R19 (verified 299.9us, absmax 0.0039) + hoist e@Wk out of the serial
// step loop. R19 counters: MfmaUtil 21.7 / VALUBusy 32.9 / Occ 22.6 / HBM 2.5%
// -> latency-bound serial LSTM. Half of each step's z-GEMM K (the e@Wk part,
// kt=2,3) is time-invariant: precompute xg = e@Wk + b once per 16-step chunk
// as a dense M=64 GEMM (full 16-row MFMA utilization), store bf16 in LDS.
// Per-step MFMA chain 4->2 (K=128->64), total MFMA -37.5%, bias folded into
// xg. xg bf16 rounding (~2e-4) is ~10x below the existing bf16-h feedback
// error, so absmax should hold at 0.0039. Everything else (2-barrier step,
// gates on 200 threads, dense head, clamps) is byte-identical to R19.

typedef unsigned short u16;
typedef unsigned int   u32;
typedef float f32x4 __attribute__((ext_vector_type(4)));
typedef short s16x8 __attribute__((ext_vector_type(8)));

__device__ __forceinline__ float bf2f(u16 u){
  union { u32 i; float f; } v; v.i = ((u32)u) << 16; return v.f;
}
__device__ __forceinline__ u16 f2bf(float f){
  union { float fl; u32 i; } v; v.fl = f;
  u32 r = v.i + 0x7fffu + ((v.i >> 16) & 1u);   // RNE
  return (u16)(r >> 16);
}
__device__ __forceinline__ float frcp(float x){ return __builtin_amdgcn_rcpf(x); }
__device__ __forceinline__ float sigm_f(float x){          // fast sigmoid
  float e = __expf(-x);
  return frcp(1.f + e);
}
__device__ __forceinline__ float tanh_f(float x){          // fast tanh, clamped
  x = fminf(fmaxf(x, -15.f), 15.f);
  float e = __expf(-2.f * x);
  return (1.f - e) * frcp(1.f + e);
}
__device__ __forceinline__ f32x4 mf(s16x8 a, s16x8 b, f32x4 c){
  return __builtin_amdgcn_mfma_f32_16x16x32_bf16(a, b, c, 0, 0, 0);
}
__device__ __forceinline__ float ldf(const void* p, int i, bool f32in){
  if (f32in) return ((const float*)p)[i];
  return bf2f(((const u16*)p)[i]);
}

#define TPB 256
#define RPB 4      // batch rows per block -> 512 blocks, 2 blocks/CU

extern "C" __global__ __launch_bounds__(TPB, 2) void LSTM_Seq2Dis_15272903704706_kernel(
    const int* idx, const void* emb, const void* Wk, const void* Uk,
    const void* bias, const void* W1, const void* b1,
    const void* W2, const void* b2, float* out)
{
  __shared__ __align__(16) u16 ebuf[4][2][512];   // e A-frags for xg GEMM (8 KB)
  __shared__ __align__(16) u16 xgl[16][4][212];   // xg+b, bf16, [sl][r][col] (26.5 KB)
  __shared__ __align__(16) u16 abuf[2][1024];     // h frags, double buffer
  __shared__ __align__(16) u16 hbuf[4][2][512];   // chunk h for dense head
  __shared__ __align__(16) u16 dwork[4][2][512];  // per-wave d1 scratch
  __shared__ float zl[4*212];                     // z[4][200] stride 212
  __shared__ float cl[4*52];                      // cell state
  __shared__ float bl[208];                       // LSTM bias
  __shared__ int   tokl[1024];                    // token ids [s][r]
  __shared__ int   s_f32;

  const int tid = threadIdx.x;
  const int wv  = tid >> 6, ln = tid & 63;
  const int r0  = blockIdx.x * RPB;

  if (tid == 0){
    const u32* ew = (const u32*)emb;
    int hits = 0;
    for (int i = 0; i < 64; i++){
      u32 ef = (ew[i] >> 7) & 0xFFu;
      if (ef >= 112u && ef <= 127u) hits++;
    }
    s_f32 = (hits < 32) ? 1 : 0;
  }

  // ebuf must be zero-padded once: k=50..63 slots are never written by the
  // gather; garbage bf16 (possible NaN) x zero B-frag would poison the acc.
  for (int i = tid; i < 4*2*512; i += TPB) ((u16*)ebuf)[i] = 0;
  for (int i = tid; i < 2*1024;  i += TPB) ((u16*)abuf)[i]  = 0;
  for (int i = tid; i < 4*2*512; i += TPB) ((u16*)hbuf)[i]  = 0;
  for (int i = tid; i < 4*52;    i += TPB) cl[i] = 0.f;
  for (int i = tid; i < 1024;    i += TPB){
    int r = i & 3, s = i >> 2;
    tokl[i] = idx[(r0 + r)*256 + s];
  }
  __syncthreads();
  const bool f32in = (s_f32 != 0);
  for (int i = tid; i < 208; i += TPB) bl[i] = (i < 200) ? ldf(bias, i, f32in) : 0.f;

  // ---- B-fragments: Uk (recurrent, per-step) and Wk (input, per-chunk), K=64 ----
  // STATIC indexing only (R16 spill fix): wave owns nt = wv + 4t, t = 0..3.
  s16x8 ukf[4][2], wkf[4][2];
  #pragma unroll
  for (int t = 0; t < 4; t++){
    const int n = (wv + 4*t)*16 + (ln & 15);
    #pragma unroll
    for (int kt = 0; kt < 2; kt++){
      s16x8 u, w;
      #pragma unroll
      for (int j = 0; j < 8; j++){
        const int k = kt*32 + ((ln >> 4) << 3) + j;
        float uu = 0.f, ww = 0.f;
        if (n < 200 && k < 50){
          uu = ldf(Uk, k*200 + n, f32in);
          ww = ldf(Wk, k*200 + n, f32in);
        }
        u[j] = (short)f2bf(uu);
        w[j] = (short)f2bf(ww);
      }
      ukf[t][kt] = u; wkf[t][kt] = w;
    }
  }

  // ---- dense W1 fragments + b1/W2 (static loops) ----
  s16x8 w1f[4][2];
  float b1v[4], w2v[4];
  #pragma unroll
  for (int nt = 0; nt < 4; nt++){
    int c = nt*16 + (ln & 15);
    b1v[nt] = (c < 50) ? ldf(b1, c, f32in) : 0.f;
    w2v[nt] = (c < 50) ? ldf(W2, c, f32in) : 0.f;
    #pragma unroll
    for (int kt = 0; kt < 2; kt++){
      s16x8 v;
      #pragma unroll
      for (int j = 0; j < 8; j++){
        int k = kt*32 + ((ln >> 4) << 3) + j;
        v[j] = (short)((k < 50 && c < 50) ? f2bf(ldf(W1, k*50 + c, f32in)) : (u16)0);
      }
      w1f[nt][kt] = v;
    }
  }
  const float b2s = ldf(b2, 0, f32in);

  const int gr = tid / 50, gj = tid - gr*50;      // threads 0..199 own (gr,gj)
  const int foff = (gj >> 5)*512 + (gr + (((gj & 31) >> 3) << 4))*8 + (gj & 7);
  __syncthreads();

  for (int ch = 0; ch < 16; ch++){
    const int tc = ch*16;

    // ---- chunk gather: e into A-frag layout (M=64 rows = sl*4+r, K=50) ----
    if (tid < 200){
      float ev[16];
      #pragma unroll
      for (int sl = 0; sl < 16; sl++)
        ev[sl] = ldf(emb, tokl[(tc + sl)*4 + gr]*50 + gj, f32in);
      const int kf = gj >> 5;
      const int eo = ((gj & 31) >> 3) << 4;
      const int jj = gj & 7;
      #pragma unroll
      for (int sl = 0; sl < 16; sl++){
        const int m = sl*4 + gr;
        ebuf[m >> 4][kf][(((m & 15) + eo) << 3) + jj] = f2bf(ev[sl]);
      }
    }
    __syncthreads();

    // ---- chunk precompute: xg = e(64x50) @ Wk(50x200) + b, full-M MFMA ----
    #pragma unroll
    for (int mt = 0; mt < 4; mt++){
      s16x8 e0 = *(const s16x8*)&ebuf[mt][0][ln*8];
      s16x8 e1 = *(const s16x8*)&ebuf[mt][1][ln*8];
      #pragma unroll
      for (int t = 0; t < 4; t++){
        f32x4 acc = {0.f,0.f,0.f,0.f};
        acc = mf(e0, wkf[t][0], acc);
        acc = mf(e1, wkf[t][1], acc);
        const int col = (wv + 4*t)*16 + (ln & 15);
        if (col < 200){
          const float bv = bl[col];
          #pragma unroll
          for (int r = 0; r < 4; r++){
            const int m = mt*16 + ((ln >> 4) << 2) + r;   // global row = sl*4+rr
            xgl[m >> 2][m & 3][col] = f2bf(acc[r] + bv);
          }
        }
      }
    }
    __syncthreads();

    for (int sl = 0; sl < 16; sl++){
      const int s   = tc + sl;
      const int cur = s & 1, nxt = cur ^ 1;

      // ---- phase A: z = xg[sl] + h(4x64) @ Uk(64x256) via MFMA (K=64) ----
      s16x8 av0 = *(const s16x8*)&abuf[cur][ln*8];
      s16x8 av1 = *(const s16x8*)&abuf[cur][512 + ln*8];
      #pragma unroll
      for (int t = 0; t < 4; t++){
        const int col = (wv + 4*t)*16 + (ln & 15);
        const bool wr = ((ln >> 4) == 0) && (col < 200);
        f32x4 acc = {0.f,0.f,0.f,0.f};
        if (wr){
          #pragma unroll
          for (int r = 0; r < 4; r++) acc[r] = bf2f(xgl[sl][r][col]);
        }
        acc = mf(av0, ukf[t][0], acc);
        acc = mf(av1, ukf[t][1], acc);
        if (wr){
          #pragma unroll
          for (int r = 0; r < 4; r++) zl[r*212 + col] = acc[r];
        }
      }
      __syncthreads();

      // ---- phase B: gates (bias already in xg) -> c,h; h -> abuf[nxt]+hbuf ----
      if (tid < 200){
        float zi = zl[gr*212 + gj];
        float zf = zl[gr*212 + 50 + gj];
        float zg = zl[gr*212 + 100 + gj];
        float zo = zl[gr*212 + 150 + gj];
        float iv = sigm_f(zi), fv = sigm_f(zf), gv = tanh_f(zg), ov = sigm_f(zo);
        float c  = fv * cl[gr*52 + gj] + iv * gv;
        cl[gr*52 + gj] = c;
        u16 hb = f2bf(ov * tanh_f(c));
        abuf[nxt][foff] = hb;
        int m = sl*4 + gr;
        hbuf[m >> 4][gj >> 5][((m & 15) + (((gj & 31) >> 3) << 4))*8 + (gj & 7)] = hb;
      }

      // ---- dense head once per chunk (wave-private M-tile) ----
      if (sl == 15){
        __syncthreads();
        s16x8 a0 = *(const s16x8*)&hbuf[wv][0][ln*8];
        s16x8 a1 = *(const s16x8*)&hbuf[wv][1][ln*8];
        #pragma unroll
        for (int nt = 0; nt < 4; nt++){             // d1 = relu(h@W1+b1)
          f32x4 acc = {0.f,0.f,0.f,0.f};
          acc = mf(a0, w1f[nt][0], acc);
          acc = mf(a1, w1f[nt][1], acc);
          int c = nt*16 + (ln & 15);
          #pragma unroll
          for (int r = 0; r < 4; r++){
            float v = fmaxf(acc[r] + b1v[nt], 0.f);
            int row16 = ((ln >> 4) << 2) + r;
            dwork[wv][c >> 5][(row16 + (((c & 31) >> 3) << 4))*8 + (c & 7)] = f2bf(v);
          }
        }
        s16x8 d0 = *(const s16x8*)&dwork[wv][0][ln*8];
        s16x8 d1 = *(const s16x8*)&dwork[wv][1][ln*8];
        float part[4] = {0.f,0.f,0.f,0.f};
        #pragma unroll
        for (int nt = 0; nt < 4; nt++){             // d2 = relu(d1@W1+b1) . W2
          f32x4 acc = {0.f,0.f,0.f,0.f};
          acc = mf(d0, w1f[nt][0], acc);
          acc = mf(d1, w1f[nt][1], acc);
          #pragma unroll
          for (int r = 0; r < 4; r++)
            part[r] += fmaxf(acc[r] + b1v[nt], 0.f) * w2v[nt];
        }
        #pragma unroll
        for (int d = 1; d < 16; d <<= 1)
          #pragma unroll
          for (int r = 0; r < 4; r++) part[r] += __shfl_xor(part[r], d, 16);
        if ((ln & 15) == 0){
          int q = ln >> 4;
          #pragma unroll
          for (int r = 0; r < 4; r++){
            int m = wv*16 + (q << 2) + r;
            int sl4 = m >> 2, rb = m & 3;
            float z = part[r] + b2s;
            z = fmaxf(fminf(z, 1.0f), -1.0f);       // safety clamp
            out[(r0 + rb)*256 + tc + sl4] = sigm_f(z);
          }
        }
      }
      __syncthreads();
    }
  }
}

extern "C" void kernel_launch(void* const* d_in, const int* in_sizes, int n_in,
                              void* d_out, int out_size, void* d_ws, size_t ws_size,
                              hipStream_t stream) {
  (void)in_sizes; (void)n_in; (void)out_size; (void)d_ws; (void)ws_size;
  hipLaunchKernelGGL(LSTM_Seq2Dis_15272903704706_kernel,
                     dim3(512), dim3(TPB), 0, stream,
                     (const int*)d_in[0], d_in[1], d_in[2], d_in[3], d_in[4],
                     d_in[5], d_in[6], d_in[7], d_in[8], (float*)d_out);
}